// Round 3
// baseline (329.105 us; speedup 1.0000x reference)
//
#include <hip/hip_runtime.h>
#include <math.h>

#define R_BINS 64
#define Z_BINS 64
#define NBINS (R_BINS * Z_BINS)
#define BLOCK 256
#define GRID 2048
#define NSLAB 64            // private global histogram slabs (1 MB in d_ws)

static constexpr float DR     = 10.0f / 64.0f;   // 0.15625 (exact in fp32)
static constexpr float DZ     = 4.0f  / 64.0f;   // 0.0625  (exact in fp32)
static constexpr float INV_DR = 6.4f;
static constexpr float INV_DZ = 16.0f;

__device__ __forceinline__ void bin_one(float x, float y, float z, float m,
                                        float* lbins) {
    const float r = sqrtf(x * x + y * y);
    const int i = (int)(r * INV_DR);              // r >= 0, trunc == floor
    const int j = (int)floorf((z + 2.0f) * INV_DZ);
    if (i < R_BINS && (unsigned)j < (unsigned)Z_BINS) {
        atomicAdd(&lbins[i * Z_BINS + j], m);     // LDS fp32 atomic: native ds_add
    }
}

// 8 particles per thread-iteration: 6 pos float4 + 2 mass float4 = 8
// independent loads issued back-to-back (32 VGPRs of payload in flight).
// Block-private LDS histogram; drain into one of NSLAB private global slabs
// so per-address atomic contention is GRID/NSLAB = 32, not GRID.
__global__ __launch_bounds__(BLOCK) void hist_kernel(const float4* __restrict__ pos4,
                                                     const float4* __restrict__ mass4,
                                                     float* __restrict__ slabs,
                                                     int n8) {
    __shared__ float lbins[NBINS];                // 16 KB
    for (int b = threadIdx.x; b < NBINS; b += BLOCK) lbins[b] = 0.0f;
    __syncthreads();

    const int stride = gridDim.x * BLOCK;
    for (int q = blockIdx.x * BLOCK + threadIdx.x; q < n8; q += stride) {
        const float4* pb = pos4 + (size_t)6 * q;
        const float4 p0 = pb[0];
        const float4 p1 = pb[1];
        const float4 p2 = pb[2];
        const float4 p3 = pb[3];
        const float4 p4 = pb[4];
        const float4 p5 = pb[5];
        const float4 ma = mass4[2 * q];
        const float4 mb = mass4[2 * q + 1];

        bin_one(p0.x, p0.y, p0.z, ma.x, lbins);
        bin_one(p0.w, p1.x, p1.y, ma.y, lbins);
        bin_one(p1.z, p1.w, p2.x, ma.z, lbins);
        bin_one(p2.y, p2.z, p2.w, ma.w, lbins);
        bin_one(p3.x, p3.y, p3.z, mb.x, lbins);
        bin_one(p3.w, p4.x, p4.y, mb.y, lbins);
        bin_one(p4.z, p4.w, p5.x, mb.z, lbins);
        bin_one(p5.y, p5.z, p5.w, mb.w, lbins);
    }

    __syncthreads();
    float* slab = slabs + (size_t)(blockIdx.x % NSLAB) * NBINS;
    for (int b = threadIdx.x; b < NBINS; b += BLOCK) {
        const float v = lbins[b];
        if (v != 0.0f) atomicAdd(&slab[b], v);
    }
}

// Tail for n % 8 != 0 (not hit at N=16777216; kept for robustness)
__global__ void tail_kernel(const float* __restrict__ pos,
                            const float* __restrict__ mass,
                            float* __restrict__ slabs,
                            int start, int n) {
    const int t = start + blockIdx.x * blockDim.x + threadIdx.x;
    if (t < n) {
        const float x = pos[3 * t], y = pos[3 * t + 1], z = pos[3 * t + 2];
        const float r = sqrtf(x * x + y * y);
        const int i = (int)(r * INV_DR);
        const int j = (int)floorf((z + 2.0f) * INV_DZ);
        if (i < R_BINS && (unsigned)j < (unsigned)Z_BINS) {
            atomicAdd(&slabs[i * Z_BINS + j], mass[t]);
        }
    }
}

// Sum the NSLAB private histograms and apply 1/volume. 4096 threads.
__global__ __launch_bounds__(256) void reduce_finalize_kernel(
        const float* __restrict__ slabs, float* __restrict__ out) {
    const int idx = blockIdx.x * blockDim.x + threadIdx.x;
    if (idx < NBINS) {
        float s = 0.0f;
#pragma unroll 8
        for (int k = 0; k < NSLAB; ++k) s += slabs[(size_t)k * NBINS + idx];
        const int i = idx / Z_BINS;
        const float r0 = (float)i * DR;
        const float r1 = (float)(i + 1) * DR;
        const float area = (float)M_PI * (r1 * r1 - r0 * r0);
        out[idx] = s / (area * DZ);
    }
}

extern "C" void kernel_launch(void* const* d_in, const int* in_sizes, int n_in,
                              void* d_out, int out_size, void* d_ws, size_t ws_size,
                              hipStream_t stream) {
    const float* positions = (const float*)d_in[0];  // (N,3) interleaved xyz
    const float* masses    = (const float*)d_in[1];  // (N,)
    float* out   = (float*)d_out;                    // (64*64,)
    float* slabs = (float*)d_ws;                     // NSLAB * 16 KB = 1 MB

    const int n = in_sizes[1];
    const int n8 = n / 8;
    const int rem = n - n8 * 8;

    // d_ws is re-poisoned to 0xAA before every timed call — zero the slabs.
    hipMemsetAsync(slabs, 0, (size_t)NSLAB * NBINS * sizeof(float), stream);

    hist_kernel<<<GRID, BLOCK, 0, stream>>>((const float4*)positions,
                                            (const float4*)masses, slabs, n8);
    if (rem > 0) {
        tail_kernel<<<(rem + 255) / 256, 256, 0, stream>>>(positions, masses,
                                                           slabs, n8 * 8, n);
    }
    reduce_finalize_kernel<<<(NBINS + 255) / 256, 256, 0, stream>>>(slabs, out);
}

// Round 4
// 328.725 us; speedup vs baseline: 1.0012x; 1.0012x over previous
//
#include <hip/hip_runtime.h>
#include <math.h>

#define R_BINS 64
#define Z_BINS 64
#define NBINS (R_BINS * Z_BINS)
#define BLOCK 256
#define GRID 2048
#define NSLAB 64            // private global histogram slabs (1 MB in d_ws)

static constexpr float DR     = 10.0f / 64.0f;   // 0.15625 (exact in fp32)
static constexpr float DZ     = 4.0f  / 64.0f;   // 0.0625  (exact in fp32)
static constexpr float INV_DR = 6.4f;
static constexpr float INV_DZ = 16.0f;

// NOTE: plain atomicAdd(float*) lowers to a CAS retry loop without
// -munsafe-fp-atomics (denormal semantics). unsafeAtomicAdd emits native
// ds_add_f32 / global_atomic_add_f32 on gfx950. Inputs here are normal
// floats; no denormal concern.
__device__ __forceinline__ void bin_one(float x, float y, float z, float m,
                                        float* lbins) {
    const float r = sqrtf(x * x + y * y);
    const int i = (int)(r * INV_DR);              // r >= 0, trunc == floor
    const int j = (int)floorf((z + 2.0f) * INV_DZ);
    if (i < R_BINS && (unsigned)j < (unsigned)Z_BINS) {
        unsafeAtomicAdd(&lbins[i * Z_BINS + j], m);   // native ds_add_f32
    }
}

// 8 particles per thread-iteration: 6 pos float4 + 2 mass float4 = 8
// independent loads in flight. Block-private LDS histogram; drain into one of
// NSLAB private global slabs (contention GRID/NSLAB = 32 per address).
__global__ __launch_bounds__(BLOCK) void hist_kernel(const float4* __restrict__ pos4,
                                                     const float4* __restrict__ mass4,
                                                     float* __restrict__ slabs,
                                                     int n8) {
    __shared__ float lbins[NBINS];                // 16 KB
    for (int b = threadIdx.x; b < NBINS; b += BLOCK) lbins[b] = 0.0f;
    __syncthreads();

    const int stride = gridDim.x * BLOCK;
    for (int q = blockIdx.x * BLOCK + threadIdx.x; q < n8; q += stride) {
        const float4* pb = pos4 + (size_t)6 * q;
        const float4 p0 = pb[0];
        const float4 p1 = pb[1];
        const float4 p2 = pb[2];
        const float4 p3 = pb[3];
        const float4 p4 = pb[4];
        const float4 p5 = pb[5];
        const float4 ma = mass4[2 * q];
        const float4 mb = mass4[2 * q + 1];

        bin_one(p0.x, p0.y, p0.z, ma.x, lbins);
        bin_one(p0.w, p1.x, p1.y, ma.y, lbins);
        bin_one(p1.z, p1.w, p2.x, ma.z, lbins);
        bin_one(p2.y, p2.z, p2.w, ma.w, lbins);
        bin_one(p3.x, p3.y, p3.z, mb.x, lbins);
        bin_one(p3.w, p4.x, p4.y, mb.y, lbins);
        bin_one(p4.z, p4.w, p5.x, mb.z, lbins);
        bin_one(p5.y, p5.z, p5.w, mb.w, lbins);
    }

    __syncthreads();
    float* slab = slabs + (size_t)(blockIdx.x % NSLAB) * NBINS;
    for (int b = threadIdx.x; b < NBINS; b += BLOCK) {
        const float v = lbins[b];
        if (v != 0.0f) unsafeAtomicAdd(&slab[b], v);   // native global_atomic_add_f32
    }
}

// Tail for n % 8 != 0 (not hit at N=16777216; kept for robustness)
__global__ void tail_kernel(const float* __restrict__ pos,
                            const float* __restrict__ mass,
                            float* __restrict__ slabs,
                            int start, int n) {
    const int t = start + blockIdx.x * blockDim.x + threadIdx.x;
    if (t < n) {
        const float x = pos[3 * t], y = pos[3 * t + 1], z = pos[3 * t + 2];
        const float r = sqrtf(x * x + y * y);
        const int i = (int)(r * INV_DR);
        const int j = (int)floorf((z + 2.0f) * INV_DZ);
        if (i < R_BINS && (unsigned)j < (unsigned)Z_BINS) {
            unsafeAtomicAdd(&slabs[i * Z_BINS + j], mass[t]);
        }
    }
}

// Sum the NSLAB private histograms and apply 1/volume. 4096 threads.
__global__ __launch_bounds__(256) void reduce_finalize_kernel(
        const float* __restrict__ slabs, float* __restrict__ out) {
    const int idx = blockIdx.x * blockDim.x + threadIdx.x;
    if (idx < NBINS) {
        float s = 0.0f;
#pragma unroll 8
        for (int k = 0; k < NSLAB; ++k) s += slabs[(size_t)k * NBINS + idx];
        const int i = idx / Z_BINS;
        const float r0 = (float)i * DR;
        const float r1 = (float)(i + 1) * DR;
        const float area = (float)M_PI * (r1 * r1 - r0 * r0);
        out[idx] = s / (area * DZ);
    }
}

extern "C" void kernel_launch(void* const* d_in, const int* in_sizes, int n_in,
                              void* d_out, int out_size, void* d_ws, size_t ws_size,
                              hipStream_t stream) {
    const float* positions = (const float*)d_in[0];  // (N,3) interleaved xyz
    const float* masses    = (const float*)d_in[1];  // (N,)
    float* out   = (float*)d_out;                    // (64*64,)
    float* slabs = (float*)d_ws;                     // NSLAB * 16 KB = 1 MB

    const int n = in_sizes[1];
    const int n8 = n / 8;
    const int rem = n - n8 * 8;

    // d_ws is re-poisoned to 0xAA before every timed call — zero the slabs.
    hipMemsetAsync(slabs, 0, (size_t)NSLAB * NBINS * sizeof(float), stream);

    hist_kernel<<<GRID, BLOCK, 0, stream>>>((const float4*)positions,
                                            (const float4*)masses, slabs, n8);
    if (rem > 0) {
        tail_kernel<<<(rem + 255) / 256, 256, 0, stream>>>(positions, masses,
                                                           slabs, n8 * 8, n);
    }
    reduce_finalize_kernel<<<(NBINS + 255) / 256, 256, 0, stream>>>(slabs, out);
}